// Round 8
// baseline (382.316 us; speedup 1.0000x reference)
//
#include <hip/hip_runtime.h>

#define CB 256        // chunk-blocks for hist/scatter
#define MAXNB 1024    // max buckets (N <= 262144)

// ---------------- bucket-sort CSR build (no global atomics) ----------------

__global__ void k_hist(const int* __restrict__ dst, int* __restrict__ histG,
                       int E, int NB, int chunk) {
  __shared__ int hist[MAXNB];
  int b = blockIdx.x, tid = threadIdx.x;
  for (int k = tid; k < NB; k += 256) hist[k] = 0;
  __syncthreads();
  int beg = b * chunk, end = min(E, beg + chunk);
  for (int i = beg + tid; i < end; i += 256) atomicAdd(&hist[dst[i] >> 8], 1);
  __syncthreads();
  for (int k = tid; k < NB; k += 256) histG[(size_t)k * CB + b] = hist[k];
}

__global__ void k_scan_local(const int* __restrict__ in, int* __restrict__ out,
                             int* __restrict__ blockSums, int n) {
  __shared__ int wsum[16];
  __shared__ int wpre[16];
  int tid = threadIdx.x;
  int gid = blockIdx.x * 1024 + tid;
  int v = (gid < n) ? in[gid] : 0;
  int lane = tid & 63, wv = tid >> 6;
  int x = v;
#pragma unroll
  for (int d = 1; d < 64; d <<= 1) {
    int t = __shfl_up(x, d);
    if (lane >= d) x += t;
  }
  if (lane == 63) wsum[wv] = x;
  __syncthreads();
  if (tid == 0) {
    int run = 0;
#pragma unroll
    for (int i = 0; i < 16; ++i) { wpre[i] = run; run += wsum[i]; }
    blockSums[blockIdx.x] = run;
  }
  __syncthreads();
  if (gid < n) out[gid] = x - v + wpre[wv];
}

// parallel scan of block sums (single block, 256 threads, nb <= 256)
__global__ void k_scan_blocks(const int* __restrict__ blockSums, int* __restrict__ blockOffs, int nb) {
  __shared__ int wtot[4];
  int tid = threadIdx.x;
  int lane = tid & 63, w = tid >> 6;
  int v = (tid < nb) ? blockSums[tid] : 0;
  int x = v;
#pragma unroll
  for (int d = 1; d < 64; d <<= 1) {
    int t = __shfl_up(x, d);
    if (lane >= d) x += t;
  }
  if (lane == 63) wtot[w] = x;
  __syncthreads();
  int pre = 0;
  for (int i = 0; i < w; ++i) pre += wtot[i];
  int ex = x - v + pre;
  if (tid < nb) blockOffs[tid] = ex;
  if (tid == nb - 1) blockOffs[nb] = ex + v;
}

__global__ void k_scatter(const int* __restrict__ src, const int* __restrict__ dst,
                          const int* __restrict__ histS, const int* __restrict__ blockOffs,
                          unsigned* __restrict__ recs, int E, int NB, int chunk) {
  __shared__ int cur[MAXNB];
  int b = blockIdx.x, tid = threadIdx.x;
  for (int k = tid; k < NB; k += 256) {
    int gid = k * CB + b;
    cur[k] = histS[gid] + blockOffs[gid >> 10];
  }
  __syncthreads();
  int beg = b * chunk, end = min(E, beg + chunk);
  for (int i = beg + tid; i < end; i += 256) {
    int s = src[i], d = dst[i];
    int pos = atomicAdd(&cur[d >> 8], 1);
    recs[pos] = ((unsigned)s << 8) | (unsigned)(d & 255);
  }
}

// per-bucket CSR finalize; also writes inv_sqrt and prescaled xp = x * inv_sqrt
__global__ void k_build(const unsigned* __restrict__ recs, const int* __restrict__ histS,
                        const int* __restrict__ blockOffs, const float* __restrict__ x,
                        int* __restrict__ offs, float* __restrict__ inv_sqrt,
                        float* __restrict__ xp, int* __restrict__ srcs,
                        int N, int NB, int E) {
  __shared__ int cnt[256];
  __shared__ int cur[256];
  __shared__ int wtot[4];
  int k = blockIdx.x, tid = threadIdx.x;
  int g0 = k * CB;
  int ebeg = histS[g0] + blockOffs[g0 >> 10];
  int eend = E;
  if (k + 1 < NB) {
    int g1 = (k + 1) * CB;
    eend = histS[g1] + blockOffs[g1 >> 10];
  }
  cnt[tid] = 0;
  __syncthreads();
  for (int i = ebeg + tid; i < eend; i += 256) atomicAdd(&cnt[recs[i] & 255u], 1);
  __syncthreads();
  int v = cnt[tid];
  int lane = tid & 63, w = tid >> 6;
  int x_ = v;
#pragma unroll
  for (int d = 1; d < 64; d <<= 1) {
    int t = __shfl_up(x_, d);
    if (lane >= d) x_ += t;
  }
  if (lane == 63) wtot[w] = x_;
  __syncthreads();
  int pre = 0;
  for (int i = 0; i < w; ++i) pre += wtot[i];
  int gpos = ebeg + (x_ - v) + pre;
  int node = k * 256 + tid;
  if (node < N) {
    offs[node] = gpos;
    float is = rsqrtf(1.0f + (float)v);
    inv_sqrt[node] = is;
    const float* xr = x + (size_t)node * 5;
    float* xo = xp + (size_t)node * 5;
    xo[0] = xr[0] * is; xo[1] = xr[1] * is; xo[2] = xr[2] * is;
    xo[3] = xr[3] * is; xo[4] = xr[4] * is;
  }
  cur[tid] = gpos;
  if (k == NB - 1 && tid == 0) offs[N] = E;
  __syncthreads();
  for (int i = ebeg + tid; i < eend; i += 256) {
    unsigned r = recs[i];
    int pos = atomicAdd(&cur[r & 255u], 1);
    srcs[pos] = (int)(r >> 8);
  }
}

// ---------------- layer kernels ----------------

// layers 1+2a fused, 2 nodes/wave; xp pre-scaled so edge loop is pure adds.
// Output in SLICED+prescaled layout: hS[slice][node][8] = h2raw * inv_sqrt[node]
__global__ void k_l12(const float* __restrict__ xp, const int* __restrict__ offs,
                      const int* __restrict__ srcs, const float* __restrict__ inv_sqrt,
                      const float* __restrict__ W1, const float* __restrict__ b1,
                      const float* __restrict__ W2, float* __restrict__ hS, int n) {
  __shared__ float hrow[4][2][64];
  int tid = threadIdx.x;
  int lane = tid & 63, w = tid >> 6;
  int hl = lane & 31, half = lane >> 5;
  int slice = lane >> 3, feat = lane & 7;
  float w1r[5];
#pragma unroll
  for (int k = 0; k < 5; ++k) w1r[k] = W1[k * 64 + lane];
  float bias = b1[lane];
  float wreg[64];
#pragma unroll
  for (int k = 0; k < 64; ++k) wreg[k] = W2[k * 64 + lane];
  float* slotA = &hrow[w][0][0];
  float* slotB = &hrow[w][1][0];
  int wid0 = (blockIdx.x * blockDim.x + tid) >> 6;
  int nw = (gridDim.x * blockDim.x) >> 6;
  for (int i2 = wid0 * 2; i2 < n; i2 += nw * 2) {
    int iA = i2, iB = i2 + 1;
    int node = (half == 0) ? iA : iB;
    bool valid = node < n;
    float a0 = 0.f, a1 = 0.f, a2 = 0.f, a3 = 0.f, a4 = 0.f;
    float isd = 0.f;
    if (valid) {
      isd = inv_sqrt[node];
      int beg = offs[node], end = offs[node + 1];
      for (int j = beg + hl; j < end; j += 32) {
        int s = srcs[j];
        const float* xs = xp + (size_t)s * 5;
        float4 xv = *(const float4*)xs;   // 4B-aligned dwordx4 (HW-legal)
        float x4 = xs[4];
        a0 += xv.x; a1 += xv.y; a2 += xv.z; a3 += xv.w; a4 += x4;
      }
    }
#pragma unroll
    for (int d = 16; d; d >>= 1) {
      a0 += __shfl_xor(a0, d); a1 += __shfl_xor(a1, d); a2 += __shfl_xor(a2, d);
      a3 += __shfl_xor(a3, d); a4 += __shfl_xor(a4, d);
    }
    if (valid) {
      const float* xi = xp + (size_t)node * 5;
      a0 = (a0 + xi[0]) * isd; a1 = (a1 + xi[1]) * isd; a2 = (a2 + xi[2]) * isd;
      a3 = (a3 + xi[3]) * isd; a4 = (a4 + xi[4]) * isd;
    }
    float aA0 = __shfl(a0, hl),      aA1 = __shfl(a1, hl),      aA2 = __shfl(a2, hl);
    float aA3 = __shfl(a3, hl),      aA4 = __shfl(a4, hl);
    float aB0 = __shfl(a0, hl | 32), aB1 = __shfl(a1, hl | 32), aB2 = __shfl(a2, hl | 32);
    float aB3 = __shfl(a3, hl | 32), aB4 = __shfl(a4, hl | 32);
    float isdA = __shfl(isd, 0), isdB = __shfl(isd, 32);
    float hA = bias;
    hA = fmaf(aA0, w1r[0], hA); hA = fmaf(aA1, w1r[1], hA); hA = fmaf(aA2, w1r[2], hA);
    hA = fmaf(aA3, w1r[3], hA); hA = fmaf(aA4, w1r[4], hA);
    hA = fmaxf(hA, 0.f);
    float hB = bias;
    hB = fmaf(aB0, w1r[0], hB); hB = fmaf(aB1, w1r[1], hB); hB = fmaf(aB2, w1r[2], hB);
    hB = fmaf(aB3, w1r[3], hB); hB = fmaf(aB4, w1r[4], hB);
    hB = fmaxf(hB, 0.f);
    slotA[lane] = hA;
    slotB[lane] = hB;
    float ac0 = 0.f, ac1 = 0.f, ac2 = 0.f, ac3 = 0.f;
#pragma unroll
    for (int k4 = 0; k4 < 16; ++k4) {
      float4 hq = *(const float4*)&slotA[k4 * 4];
      ac0 = fmaf(hq.x, wreg[k4 * 4],     ac0);
      ac1 = fmaf(hq.y, wreg[k4 * 4 + 1], ac1);
      ac2 = fmaf(hq.z, wreg[k4 * 4 + 2], ac2);
      ac3 = fmaf(hq.w, wreg[k4 * 4 + 3], ac3);
    }
    hS[((size_t)slice * n + iA) * 8 + feat] = ((ac0 + ac1) + (ac2 + ac3)) * isdA;
    if (iB < n) {
      float bc0 = 0.f, bc1 = 0.f, bc2 = 0.f, bc3 = 0.f;
#pragma unroll
      for (int k4 = 0; k4 < 16; ++k4) {
        float4 hq = *(const float4*)&slotB[k4 * 4];
        bc0 = fmaf(hq.x, wreg[k4 * 4],     bc0);
        bc1 = fmaf(hq.y, wreg[k4 * 4 + 1], bc1);
        bc2 = fmaf(hq.z, wreg[k4 * 4 + 2], bc2);
        bc3 = fmaf(hq.w, wreg[k4 * 4 + 3], bc3);
      }
      hS[((size_t)slice * n + iB) * 8 + feat] = ((bc0 + bc1) + (bc2 + bc3)) * isdB;
    }
  }
}

// sliced aggregation: slice = blockIdx&7 (pins to one XCD; its 3.2MB strip is L2-resident).
// lane = (slot 0..7, feat 0..7); inner loop is pure adds (hS pre-scaled by inv_sqrt[src]).
// Emits per-slice W3 partials: part[node][slice][2].
__global__ void k_aggS(const float* __restrict__ hS, const int* __restrict__ offs,
                       const int* __restrict__ srcs, const float* __restrict__ inv_sqrt,
                       const float* __restrict__ b2, const float* __restrict__ W3,
                       float* __restrict__ part, int n) {
  int slice = blockIdx.x & 7;
  int tid = threadIdx.x;
  int lane = tid & 63;
  int slot = lane >> 3, feat = lane & 7;
  int f = slice * 8 + feat;
  float b2v = b2[f];
  float w30 = W3[f * 2], w31 = W3[f * 2 + 1];
  const float* hbase = hS + (size_t)slice * n * 8;
  int wid0 = ((blockIdx.x >> 3) << 2) + (tid >> 6);   // 4 waves/block
  int nw = (gridDim.x >> 3) << 2;
  for (int i = wid0; i < n; i += nw) {
    int beg = offs[i], end = offs[i + 1];
    float acc0 = 0.f, acc1 = 0.f;
    int j = beg + slot;
    for (; j + 8 < end; j += 16) {
      int s0 = srcs[j], s1 = srcs[j + 8];
      acc0 += hbase[(size_t)s0 * 8 + feat];
      acc1 += hbase[(size_t)s1 * 8 + feat];
    }
    if (j < end) acc0 += hbase[(size_t)srcs[j] * 8 + feat];
    float selfv = hbase[(size_t)i * 8 + feat];
    float acc = acc0 + acc1;
    acc += __shfl_xor(acc, 8);
    acc += __shfl_xor(acc, 16);
    acc += __shfl_xor(acc, 32);
    float isd = inv_sqrt[i];
    float h2 = fmaxf(fmaf(isd, acc + selfv, b2v), 0.f);
    float p0 = h2 * w30, p1 = h2 * w31;
    p0 += __shfl_xor(p0, 1); p1 += __shfl_xor(p1, 1);
    p0 += __shfl_xor(p0, 2); p1 += __shfl_xor(p1, 2);
    p0 += __shfl_xor(p0, 4); p1 += __shfl_xor(p1, 4);
    if (lane == 0) {
      float2 pr; pr.x = p0; pr.y = p1;
      *(float2*)(part + ((size_t)i * 8 + slice) * 2) = pr;
    }
  }
}

// sum the 8 slice-partials -> h3, prescaled by inv_sqrt
__global__ void k_sumpart(const float* __restrict__ part, const float* __restrict__ inv_sqrt,
                          float* __restrict__ h3p, int n) {
  int i = blockIdx.x * blockDim.x + threadIdx.x;
  if (i >= n) return;
  const float4* p = (const float4*)(part + (size_t)i * 16);
  float4 q0 = p[0], q1 = p[1], q2 = p[2], q3 = p[3];
  float is = inv_sqrt[i];
  float s0 = ((q0.x + q0.z) + (q1.x + q1.z)) + ((q2.x + q2.z) + (q3.x + q3.z));
  float s1 = ((q0.y + q0.w) + (q1.y + q1.w)) + ((q2.y + q2.w) + (q3.y + q3.w));
  float2 r; r.x = s0 * is; r.y = s1 * is;
  *(float2*)(h3p + (size_t)i * 2) = r;
}

// out = isd*(sum h3p[src] + h3p[self]) + b3   (h3p pre-scaled)
__global__ void k_agg2(const float* __restrict__ h3p, const int* __restrict__ offs,
                       const int* __restrict__ srcs, const float* __restrict__ inv_sqrt,
                       const float* __restrict__ b3, float* __restrict__ out, int n) {
  int wid = (blockIdx.x * blockDim.x + threadIdx.x) >> 6;
  int lane = threadIdx.x & 63;
  if (wid >= n) return;
  int beg = offs[wid], end = offs[wid + 1];
  float a0 = 0.f, a1 = 0.f;
  for (int j = beg + lane; j < end; j += 64) {
    int s = srcs[j];
    float2 hv = *(const float2*)(h3p + (size_t)s * 2);
    a0 += hv.x; a1 += hv.y;
  }
#pragma unroll
  for (int d = 32; d; d >>= 1) { a0 += __shfl_xor(a0, d); a1 += __shfl_xor(a1, d); }
  if (lane == 0) {
    float isd = inv_sqrt[wid];
    float2 self = *(const float2*)(h3p + (size_t)wid * 2);
    out[(size_t)wid * 2]     = fmaf(isd, a0 + self.x, b3[0]);
    out[(size_t)wid * 2 + 1] = fmaf(isd, a1 + self.y, b3[1]);
  }
}

// ---------------- launcher ----------------

extern "C" void kernel_launch(void* const* d_in, const int* in_sizes, int n_in,
                              void* d_out, int out_size, void* d_ws, size_t ws_size,
                              hipStream_t stream) {
  const float* x  = (const float*)d_in[0];
  const int*   ei = (const int*)d_in[1];
  const float* W1 = (const float*)d_in[2];
  const float* b1 = (const float*)d_in[3];
  const float* W2 = (const float*)d_in[4];
  const float* b2 = (const float*)d_in[5];
  const float* W3 = (const float*)d_in[6];
  const float* b3 = (const float*)d_in[7];
  float* out = (float*)d_out;

  const int N = in_sizes[0] / 5;
  const int E = in_sizes[1] / 2;
  const int* src = ei;
  const int* dst = ei + E;

  const int NB = (N + 255) >> 8;
  const int chunk = (E + CB - 1) / CB;
  const int n2 = NB * CB;
  const int nb2 = (n2 + 1023) / 1024;   // <= 256

  char* p = (char*)d_ws;
  auto alloc = [&](size_t bytes) {
    char* r = p;
    p += (bytes + 255) & ~(size_t)255;
    return r;
  };
  int*      histG     = (int*)alloc((size_t)n2 * 4);
  int*      histS     = (int*)alloc((size_t)n2 * 4);
  int*      blockSums = (int*)alloc((size_t)nb2 * 4);
  int*      blockOffs = (int*)alloc((size_t)(nb2 + 1) * 4);
  unsigned* recs      = (unsigned*)alloc((size_t)E * 4);
  int*      srcs      = (int*)alloc((size_t)E * 4);
  int*      offs      = (int*)alloc((size_t)(N + 1) * 4);
  float*    inv_sqrt  = (float*)alloc((size_t)N * 4);
  float*    xp        = (float*)alloc((size_t)N * 5 * 4);
  float*    hS        = (float*)alloc((size_t)N * 64 * 4);
  float*    part      = (float*)alloc((size_t)N * 16 * 4);
  float*    h3p       = (float*)alloc((size_t)N * 2 * 4);

  const int wavesBlocks = (N * 64 + 255) / 256;  // one wave per node

  // CSR build via stable bucket sort — zero global atomics
  k_hist<<<CB, 256, 0, stream>>>(dst, histG, E, NB, chunk);
  k_scan_local<<<nb2, 1024, 0, stream>>>(histG, histS, blockSums, n2);
  k_scan_blocks<<<1, 256, 0, stream>>>(blockSums, blockOffs, nb2);
  k_scatter<<<CB, 256, 0, stream>>>(src, dst, histS, blockOffs, recs, E, NB, chunk);
  k_build<<<NB, 256, 0, stream>>>(recs, histS, blockOffs, x, offs, inv_sqrt, xp, srcs, N, NB, E);

  // layers 1+2a fused: hS[slice][node][8] = (relu((A x) W1 + b1) @ W2) * inv_sqrt
  k_l12<<<2048, 256, 0, stream>>>(xp, offs, srcs, inv_sqrt, W1, b1, W2, hS, N);
  // layers 2b+3a: XCD-sliced gather + per-slice W3 partials
  k_aggS<<<2048, 256, 0, stream>>>(hS, offs, srcs, inv_sqrt, b2, W3, part, N);
  k_sumpart<<<(N + 255) / 256, 256, 0, stream>>>(part, inv_sqrt, h3p, N);
  // layer 3 aggregation
  k_agg2<<<wavesBlocks, 256, 0, stream>>>(h3p, offs, srcs, inv_sqrt, b3, out, N);
}

// Round 9
// 249.609 us; speedup vs baseline: 1.5317x; 1.5317x over previous
//
#include <hip/hip_runtime.h>

#define CB 256        // chunk-blocks for hist/scatter
#define MAXNB 1024    // max buckets (N <= 262144)

// ---------------- bucket-sort CSR build (no global atomics) ----------------

__global__ void k_hist(const int* __restrict__ dst, int* __restrict__ histG,
                       int E, int NB, int chunk) {
  __shared__ int hist[MAXNB];
  int b = blockIdx.x, tid = threadIdx.x;
  for (int k = tid; k < NB; k += 256) hist[k] = 0;
  __syncthreads();
  int beg = b * chunk, end = min(E, beg + chunk);
  for (int i = beg + tid; i < end; i += 256) atomicAdd(&hist[dst[i] >> 8], 1);
  __syncthreads();
  for (int k = tid; k < NB; k += 256) histG[(size_t)k * CB + b] = hist[k];
}

__global__ void k_scan_local(const int* __restrict__ in, int* __restrict__ out,
                             int* __restrict__ blockSums, int n) {
  __shared__ int wsum[16];
  __shared__ int wpre[16];
  int tid = threadIdx.x;
  int gid = blockIdx.x * 1024 + tid;
  int v = (gid < n) ? in[gid] : 0;
  int lane = tid & 63, wv = tid >> 6;
  int x = v;
#pragma unroll
  for (int d = 1; d < 64; d <<= 1) {
    int t = __shfl_up(x, d);
    if (lane >= d) x += t;
  }
  if (lane == 63) wsum[wv] = x;
  __syncthreads();
  if (tid == 0) {
    int run = 0;
#pragma unroll
    for (int i = 0; i < 16; ++i) { wpre[i] = run; run += wsum[i]; }
    blockSums[blockIdx.x] = run;
  }
  __syncthreads();
  if (gid < n) out[gid] = x - v + wpre[wv];
}

// parallel scan of block sums (single block, 256 threads, nb <= 256)
__global__ void k_scan_blocks(const int* __restrict__ blockSums, int* __restrict__ blockOffs, int nb) {
  __shared__ int wtot[4];
  int tid = threadIdx.x;
  int lane = tid & 63, w = tid >> 6;
  int v = (tid < nb) ? blockSums[tid] : 0;
  int x = v;
#pragma unroll
  for (int d = 1; d < 64; d <<= 1) {
    int t = __shfl_up(x, d);
    if (lane >= d) x += t;
  }
  if (lane == 63) wtot[w] = x;
  __syncthreads();
  int pre = 0;
  for (int i = 0; i < w; ++i) pre += wtot[i];
  int ex = x - v + pre;
  if (tid < nb) blockOffs[tid] = ex;
  if (tid == nb - 1) blockOffs[nb] = ex + v;
}

__global__ void k_scatter(const int* __restrict__ src, const int* __restrict__ dst,
                          const int* __restrict__ histS, const int* __restrict__ blockOffs,
                          unsigned* __restrict__ recs, int E, int NB, int chunk) {
  __shared__ int cur[MAXNB];
  int b = blockIdx.x, tid = threadIdx.x;
  for (int k = tid; k < NB; k += 256) {
    int gid = k * CB + b;
    cur[k] = histS[gid] + blockOffs[gid >> 10];
  }
  __syncthreads();
  int beg = b * chunk, end = min(E, beg + chunk);
  for (int i = beg + tid; i < end; i += 256) {
    int s = src[i], d = dst[i];
    int pos = atomicAdd(&cur[d >> 8], 1);
    recs[pos] = ((unsigned)s << 8) | (unsigned)(d & 255);
  }
}

// per-bucket CSR finalize; also writes inv_sqrt and prescaled xp = x * inv_sqrt
__global__ void k_build(const unsigned* __restrict__ recs, const int* __restrict__ histS,
                        const int* __restrict__ blockOffs, const float* __restrict__ x,
                        int* __restrict__ offs, float* __restrict__ inv_sqrt,
                        float* __restrict__ xp, int* __restrict__ srcs,
                        int N, int NB, int E) {
  __shared__ int cnt[256];
  __shared__ int cur[256];
  __shared__ int wtot[4];
  int k = blockIdx.x, tid = threadIdx.x;
  int g0 = k * CB;
  int ebeg = histS[g0] + blockOffs[g0 >> 10];
  int eend = E;
  if (k + 1 < NB) {
    int g1 = (k + 1) * CB;
    eend = histS[g1] + blockOffs[g1 >> 10];
  }
  cnt[tid] = 0;
  __syncthreads();
  for (int i = ebeg + tid; i < eend; i += 256) atomicAdd(&cnt[recs[i] & 255u], 1);
  __syncthreads();
  int v = cnt[tid];
  int lane = tid & 63, w = tid >> 6;
  int x_ = v;
#pragma unroll
  for (int d = 1; d < 64; d <<= 1) {
    int t = __shfl_up(x_, d);
    if (lane >= d) x_ += t;
  }
  if (lane == 63) wtot[w] = x_;
  __syncthreads();
  int pre = 0;
  for (int i = 0; i < w; ++i) pre += wtot[i];
  int gpos = ebeg + (x_ - v) + pre;
  int node = k * 256 + tid;
  if (node < N) {
    offs[node] = gpos;
    float is = rsqrtf(1.0f + (float)v);
    inv_sqrt[node] = is;
    const float* xr = x + (size_t)node * 5;
    float* xo = xp + (size_t)node * 5;
    xo[0] = xr[0] * is; xo[1] = xr[1] * is; xo[2] = xr[2] * is;
    xo[3] = xr[3] * is; xo[4] = xr[4] * is;
  }
  cur[tid] = gpos;
  if (k == NB - 1 && tid == 0) offs[N] = E;
  __syncthreads();
  for (int i = ebeg + tid; i < eend; i += 256) {
    unsigned r = recs[i];
    int pos = atomicAdd(&cur[r & 255u], 1);
    srcs[pos] = (int)(r >> 8);
  }
}

// ---------------- layer kernels ----------------

// layers 1+2a fused, 2 nodes/wave; xp pre-scaled so edge loop is pure adds.
// Output prescaled, LINEAR layout: hp[node][64] = (relu((A x)W1+b1) @ W2) * inv_sqrt[node]
__global__ void k_l12(const float* __restrict__ xp, const int* __restrict__ offs,
                      const int* __restrict__ srcs, const float* __restrict__ inv_sqrt,
                      const float* __restrict__ W1, const float* __restrict__ b1,
                      const float* __restrict__ W2, float* __restrict__ hp, int n) {
  __shared__ float hrow[4][2][64];
  int tid = threadIdx.x;
  int lane = tid & 63, w = tid >> 6;
  int hl = lane & 31, half = lane >> 5;
  float w1r[5];
#pragma unroll
  for (int k = 0; k < 5; ++k) w1r[k] = W1[k * 64 + lane];
  float bias = b1[lane];
  float wreg[64];
#pragma unroll
  for (int k = 0; k < 64; ++k) wreg[k] = W2[k * 64 + lane];
  float* slotA = &hrow[w][0][0];
  float* slotB = &hrow[w][1][0];
  int wid0 = (blockIdx.x * blockDim.x + tid) >> 6;
  int nw = (gridDim.x * blockDim.x) >> 6;
  for (int i2 = wid0 * 2; i2 < n; i2 += nw * 2) {
    int iA = i2, iB = i2 + 1;
    int node = (half == 0) ? iA : iB;
    bool valid = node < n;
    float a0 = 0.f, a1 = 0.f, a2 = 0.f, a3 = 0.f, a4 = 0.f;
    float isd = 0.f;
    if (valid) {
      isd = inv_sqrt[node];
      int beg = offs[node], end = offs[node + 1];
      for (int j = beg + hl; j < end; j += 32) {
        int s = srcs[j];
        const float* xs = xp + (size_t)s * 5;
        float4 xv = *(const float4*)xs;   // 4B-aligned dwordx4 (HW-legal)
        float x4 = xs[4];
        a0 += xv.x; a1 += xv.y; a2 += xv.z; a3 += xv.w; a4 += x4;
      }
    }
#pragma unroll
    for (int d = 16; d; d >>= 1) {
      a0 += __shfl_xor(a0, d); a1 += __shfl_xor(a1, d); a2 += __shfl_xor(a2, d);
      a3 += __shfl_xor(a3, d); a4 += __shfl_xor(a4, d);
    }
    if (valid) {
      const float* xi = xp + (size_t)node * 5;
      a0 = (a0 + xi[0]) * isd; a1 = (a1 + xi[1]) * isd; a2 = (a2 + xi[2]) * isd;
      a3 = (a3 + xi[3]) * isd; a4 = (a4 + xi[4]) * isd;
    }
    float aA0 = __shfl(a0, hl),      aA1 = __shfl(a1, hl),      aA2 = __shfl(a2, hl);
    float aA3 = __shfl(a3, hl),      aA4 = __shfl(a4, hl);
    float aB0 = __shfl(a0, hl | 32), aB1 = __shfl(a1, hl | 32), aB2 = __shfl(a2, hl | 32);
    float aB3 = __shfl(a3, hl | 32), aB4 = __shfl(a4, hl | 32);
    float isdA = __shfl(isd, 0), isdB = __shfl(isd, 32);
    float hA = bias;
    hA = fmaf(aA0, w1r[0], hA); hA = fmaf(aA1, w1r[1], hA); hA = fmaf(aA2, w1r[2], hA);
    hA = fmaf(aA3, w1r[3], hA); hA = fmaf(aA4, w1r[4], hA);
    hA = fmaxf(hA, 0.f);
    float hB = bias;
    hB = fmaf(aB0, w1r[0], hB); hB = fmaf(aB1, w1r[1], hB); hB = fmaf(aB2, w1r[2], hB);
    hB = fmaf(aB3, w1r[3], hB); hB = fmaf(aB4, w1r[4], hB);
    hB = fmaxf(hB, 0.f);
    slotA[lane] = hA;
    slotB[lane] = hB;
    float ac0 = 0.f, ac1 = 0.f, ac2 = 0.f, ac3 = 0.f;
#pragma unroll
    for (int k4 = 0; k4 < 16; ++k4) {
      float4 hq = *(const float4*)&slotA[k4 * 4];
      ac0 = fmaf(hq.x, wreg[k4 * 4],     ac0);
      ac1 = fmaf(hq.y, wreg[k4 * 4 + 1], ac1);
      ac2 = fmaf(hq.z, wreg[k4 * 4 + 2], ac2);
      ac3 = fmaf(hq.w, wreg[k4 * 4 + 3], ac3);
    }
    hp[(size_t)iA * 64 + lane] = ((ac0 + ac1) + (ac2 + ac3)) * isdA;
    if (iB < n) {
      float bc0 = 0.f, bc1 = 0.f, bc2 = 0.f, bc3 = 0.f;
#pragma unroll
      for (int k4 = 0; k4 < 16; ++k4) {
        float4 hq = *(const float4*)&slotB[k4 * 4];
        bc0 = fmaf(hq.x, wreg[k4 * 4],     bc0);
        bc1 = fmaf(hq.y, wreg[k4 * 4 + 1], bc1);
        bc2 = fmaf(hq.z, wreg[k4 * 4 + 2], bc2);
        bc3 = fmaf(hq.w, wreg[k4 * 4 + 3], bc3);
      }
      hp[(size_t)iB * 64 + lane] = ((bc0 + bc1) + (bc2 + bc3)) * isdB;
    }
  }
}

// layers 2b+3a fused: h2 = relu(isd*(sum hp[src] + hp[self]) + b2); h3p = (h2 @ W3)*isd
// hp prescaled -> inner loop is PURE float4 adds, 16 rows in flight per wave.
__global__ void k_agg64w3(const float* __restrict__ hp, const int* __restrict__ offs,
                          const int* __restrict__ srcs, const float* __restrict__ inv_sqrt,
                          const float* __restrict__ b2, const float* __restrict__ W3,
                          float* __restrict__ h3p, int n) {
  int wid = (blockIdx.x * blockDim.x + threadIdx.x) >> 6;
  int lane = threadIdx.x & 63;
  if (wid >= n) return;
  int sub = lane >> 4;
  int fl  = lane & 15;
  float w30[4], w31[4];
#pragma unroll
  for (int q = 0; q < 4; ++q) {
    w30[q] = W3[(fl * 4 + q) * 2];
    w31[q] = W3[(fl * 4 + q) * 2 + 1];
  }
  int beg = offs[wid], end = offs[wid + 1];
  float isd = inv_sqrt[wid];
  float ax0 = 0.f, ay0 = 0.f, az0 = 0.f, aw0 = 0.f;
  float ax1 = 0.f, ay1 = 0.f, az1 = 0.f, aw1 = 0.f;
  int j = beg + sub;
  for (; j + 12 < end; j += 16) {
    int s0 = srcs[j], s1 = srcs[j + 4], s2 = srcs[j + 8], s3 = srcs[j + 12];
    float4 r0 = *(const float4*)(hp + (size_t)s0 * 64 + fl * 4);
    float4 r1 = *(const float4*)(hp + (size_t)s1 * 64 + fl * 4);
    float4 r2 = *(const float4*)(hp + (size_t)s2 * 64 + fl * 4);
    float4 r3 = *(const float4*)(hp + (size_t)s3 * 64 + fl * 4);
    ax0 += r0.x; ay0 += r0.y; az0 += r0.z; aw0 += r0.w;
    ax1 += r1.x; ay1 += r1.y; az1 += r1.z; aw1 += r1.w;
    ax0 += r2.x; ay0 += r2.y; az0 += r2.z; aw0 += r2.w;
    ax1 += r3.x; ay1 += r3.y; az1 += r3.z; aw1 += r3.w;
  }
  for (; j < end; j += 4) {
    int s0 = srcs[j];
    float4 r0 = *(const float4*)(hp + (size_t)s0 * 64 + fl * 4);
    ax0 += r0.x; ay0 += r0.y; az0 += r0.z; aw0 += r0.w;
  }
  float ax = ax0 + ax1, ay = ay0 + ay1, az = az0 + az1, aw = aw0 + aw1;
  ax += __shfl_xor(ax, 16); ay += __shfl_xor(ay, 16);
  az += __shfl_xor(az, 16); aw += __shfl_xor(aw, 16);
  ax += __shfl_xor(ax, 32); ay += __shfl_xor(ay, 32);
  az += __shfl_xor(az, 32); aw += __shfl_xor(aw, 32);
  float4 self = *(const float4*)(hp + (size_t)wid * 64 + fl * 4);
  float4 bb   = *(const float4*)(b2 + fl * 4);
  float hx = fmaxf(fmaf(isd, ax + self.x, bb.x), 0.f);
  float hy = fmaxf(fmaf(isd, ay + self.y, bb.y), 0.f);
  float hz = fmaxf(fmaf(isd, az + self.z, bb.z), 0.f);
  float hw = fmaxf(fmaf(isd, aw + self.w, bb.w), 0.f);
  float p0 = hx * w30[0] + hy * w30[1] + hz * w30[2] + hw * w30[3];
  float p1 = hx * w31[0] + hy * w31[1] + hz * w31[2] + hw * w31[3];
#pragma unroll
  for (int d = 8; d; d >>= 1) { p0 += __shfl_xor(p0, d); p1 += __shfl_xor(p1, d); }
  if (lane == 0) {
    h3p[(size_t)wid * 2]     = p0 * isd;
    h3p[(size_t)wid * 2 + 1] = p1 * isd;
  }
}

// out = isd*(sum h3p[src] + h3p[self]) + b3   (h3p pre-scaled -> pure adds)
__global__ void k_agg2(const float* __restrict__ h3p, const int* __restrict__ offs,
                       const int* __restrict__ srcs, const float* __restrict__ inv_sqrt,
                       const float* __restrict__ b3, float* __restrict__ out, int n) {
  int wid = (blockIdx.x * blockDim.x + threadIdx.x) >> 6;
  int lane = threadIdx.x & 63;
  if (wid >= n) return;
  int beg = offs[wid], end = offs[wid + 1];
  float a0 = 0.f, a1 = 0.f;
  for (int j = beg + lane; j < end; j += 64) {
    int s = srcs[j];
    float2 hv = *(const float2*)(h3p + (size_t)s * 2);
    a0 += hv.x; a1 += hv.y;
  }
#pragma unroll
  for (int d = 32; d; d >>= 1) { a0 += __shfl_xor(a0, d); a1 += __shfl_xor(a1, d); }
  if (lane == 0) {
    float isd = inv_sqrt[wid];
    float2 self = *(const float2*)(h3p + (size_t)wid * 2);
    out[(size_t)wid * 2]     = fmaf(isd, a0 + self.x, b3[0]);
    out[(size_t)wid * 2 + 1] = fmaf(isd, a1 + self.y, b3[1]);
  }
}

// ---------------- launcher ----------------

extern "C" void kernel_launch(void* const* d_in, const int* in_sizes, int n_in,
                              void* d_out, int out_size, void* d_ws, size_t ws_size,
                              hipStream_t stream) {
  const float* x  = (const float*)d_in[0];
  const int*   ei = (const int*)d_in[1];
  const float* W1 = (const float*)d_in[2];
  const float* b1 = (const float*)d_in[3];
  const float* W2 = (const float*)d_in[4];
  const float* b2 = (const float*)d_in[5];
  const float* W3 = (const float*)d_in[6];
  const float* b3 = (const float*)d_in[7];
  float* out = (float*)d_out;

  const int N = in_sizes[0] / 5;
  const int E = in_sizes[1] / 2;
  const int* src = ei;
  const int* dst = ei + E;

  const int NB = (N + 255) >> 8;
  const int chunk = (E + CB - 1) / CB;
  const int n2 = NB * CB;
  const int nb2 = (n2 + 1023) / 1024;   // <= 256

  char* p = (char*)d_ws;
  auto alloc = [&](size_t bytes) {
    char* r = p;
    p += (bytes + 255) & ~(size_t)255;
    return r;
  };
  int*      histG     = (int*)alloc((size_t)n2 * 4);
  int*      histS     = (int*)alloc((size_t)n2 * 4);
  int*      blockSums = (int*)alloc((size_t)nb2 * 4);
  int*      blockOffs = (int*)alloc((size_t)(nb2 + 1) * 4);
  unsigned* recs      = (unsigned*)alloc((size_t)E * 4);
  int*      srcs      = (int*)alloc((size_t)E * 4);
  int*      offs      = (int*)alloc((size_t)(N + 1) * 4);
  float*    inv_sqrt  = (float*)alloc((size_t)N * 4);
  float*    xp        = (float*)alloc((size_t)N * 5 * 4);
  float*    hp        = (float*)alloc((size_t)N * 64 * 4);
  float*    h3p       = (float*)alloc((size_t)N * 2 * 4);

  const int wavesBlocks = (N * 64 + 255) / 256;  // one wave per node

  // CSR build via stable bucket sort — zero global atomics
  k_hist<<<CB, 256, 0, stream>>>(dst, histG, E, NB, chunk);
  k_scan_local<<<nb2, 1024, 0, stream>>>(histG, histS, blockSums, n2);
  k_scan_blocks<<<1, 256, 0, stream>>>(blockSums, blockOffs, nb2);
  k_scatter<<<CB, 256, 0, stream>>>(src, dst, histS, blockOffs, recs, E, NB, chunk);
  k_build<<<NB, 256, 0, stream>>>(recs, histS, blockOffs, x, offs, inv_sqrt, xp, srcs, N, NB, E);

  // layers 1+2a fused: hp[node][64] = (relu((A x) W1 + b1) @ W2) * inv_sqrt
  k_l12<<<2048, 256, 0, stream>>>(xp, offs, srcs, inv_sqrt, W1, b1, W2, hp, N);
  // layers 2b+3a fused: h3p = (relu(isd*(sum hp) + b2) @ W3) * isd
  k_agg64w3<<<wavesBlocks, 256, 0, stream>>>(hp, offs, srcs, inv_sqrt, b2, W3, h3p, N);
  // layer 3 aggregation
  k_agg2<<<wavesBlocks, 256, 0, stream>>>(h3p, offs, srcs, inv_sqrt, b3, out, N);
}

// Round 10
// 226.067 us; speedup vs baseline: 1.6912x; 1.1041x over previous
//
#include <hip/hip_runtime.h>

#define CB 256        // chunk-blocks for hist/scatter
#define MAXNB 1024    // max buckets (N <= 262144)

// ---------------- bucket-sort CSR build (no global atomics) ----------------

__global__ void k_hist(const int* __restrict__ dst, int* __restrict__ histG,
                       int E, int NB, int chunk) {
  __shared__ int hist[MAXNB];
  int b = blockIdx.x, tid = threadIdx.x;
  for (int k = tid; k < NB; k += 256) hist[k] = 0;
  __syncthreads();
  int beg = b * chunk, end = min(E, beg + chunk);
  int nvec = (end - beg) & ~3;
  for (int i = beg + tid * 4; i < beg + nvec; i += 1024) {
    int4 d = *(const int4*)(dst + i);
    atomicAdd(&hist[d.x >> 8], 1); atomicAdd(&hist[d.y >> 8], 1);
    atomicAdd(&hist[d.z >> 8], 1); atomicAdd(&hist[d.w >> 8], 1);
  }
  for (int i = beg + nvec + tid; i < end; i += 256) atomicAdd(&hist[dst[i] >> 8], 1);
  __syncthreads();
  for (int k = tid; k < NB; k += 256) histG[(size_t)k * CB + b] = hist[k];
}

__global__ void k_scan_local(const int* __restrict__ in, int* __restrict__ out,
                             int* __restrict__ blockSums, int n) {
  __shared__ int wsum[16];
  __shared__ int wpre[16];
  int tid = threadIdx.x;
  int gid = blockIdx.x * 1024 + tid;
  int v = (gid < n) ? in[gid] : 0;
  int lane = tid & 63, wv = tid >> 6;
  int x = v;
#pragma unroll
  for (int d = 1; d < 64; d <<= 1) {
    int t = __shfl_up(x, d);
    if (lane >= d) x += t;
  }
  if (lane == 63) wsum[wv] = x;
  __syncthreads();
  if (tid == 0) {
    int run = 0;
#pragma unroll
    for (int i = 0; i < 16; ++i) { wpre[i] = run; run += wsum[i]; }
    blockSums[blockIdx.x] = run;
  }
  __syncthreads();
  if (gid < n) out[gid] = x - v + wpre[wv];
}

// parallel scan of block sums (single block, 256 threads, nb <= 256)
__global__ void k_scan_blocks(const int* __restrict__ blockSums, int* __restrict__ blockOffs, int nb) {
  __shared__ int wtot[4];
  int tid = threadIdx.x;
  int lane = tid & 63, w = tid >> 6;
  int v = (tid < nb) ? blockSums[tid] : 0;
  int x = v;
#pragma unroll
  for (int d = 1; d < 64; d <<= 1) {
    int t = __shfl_up(x, d);
    if (lane >= d) x += t;
  }
  if (lane == 63) wtot[w] = x;
  __syncthreads();
  int pre = 0;
  for (int i = 0; i < w; ++i) pre += wtot[i];
  int ex = x - v + pre;
  if (tid < nb) blockOffs[tid] = ex;
  if (tid == nb - 1) blockOffs[nb] = ex + v;
}

__global__ void k_scatter(const int* __restrict__ src, const int* __restrict__ dst,
                          const int* __restrict__ histS, const int* __restrict__ blockOffs,
                          unsigned* __restrict__ recs, int E, int NB, int chunk) {
  __shared__ int cur[MAXNB];
  int b = blockIdx.x, tid = threadIdx.x;
  for (int k = tid; k < NB; k += 256) {
    int gid = k * CB + b;
    cur[k] = histS[gid] + blockOffs[gid >> 10];
  }
  __syncthreads();
  int beg = b * chunk, end = min(E, beg + chunk);
  int nvec = (end - beg) & ~3;
  for (int i = beg + tid * 4; i < beg + nvec; i += 1024) {
    int4 s4 = *(const int4*)(src + i);
    int4 d4 = *(const int4*)(dst + i);
    int p0 = atomicAdd(&cur[d4.x >> 8], 1);
    recs[p0] = ((unsigned)s4.x << 8) | (unsigned)(d4.x & 255);
    int p1 = atomicAdd(&cur[d4.y >> 8], 1);
    recs[p1] = ((unsigned)s4.y << 8) | (unsigned)(d4.y & 255);
    int p2 = atomicAdd(&cur[d4.z >> 8], 1);
    recs[p2] = ((unsigned)s4.z << 8) | (unsigned)(d4.z & 255);
    int p3 = atomicAdd(&cur[d4.w >> 8], 1);
    recs[p3] = ((unsigned)s4.w << 8) | (unsigned)(d4.w & 255);
  }
  for (int i = beg + nvec + tid; i < end; i += 256) {
    int s = src[i], d = dst[i];
    int pos = atomicAdd(&cur[d >> 8], 1);
    recs[pos] = ((unsigned)s << 8) | (unsigned)(d & 255);
  }
}

// per-bucket CSR finalize; also writes inv_sqrt and prescaled xp = x * inv_sqrt
__global__ void k_build(const unsigned* __restrict__ recs, const int* __restrict__ histS,
                        const int* __restrict__ blockOffs, const float* __restrict__ x,
                        int* __restrict__ offs, float* __restrict__ inv_sqrt,
                        float* __restrict__ xp, int* __restrict__ srcs,
                        int N, int NB, int E) {
  __shared__ int cnt[256];
  __shared__ int cur[256];
  __shared__ int wtot[4];
  int k = blockIdx.x, tid = threadIdx.x;
  int g0 = k * CB;
  int ebeg = histS[g0] + blockOffs[g0 >> 10];
  int eend = E;
  if (k + 1 < NB) {
    int g1 = (k + 1) * CB;
    eend = histS[g1] + blockOffs[g1 >> 10];
  }
  cnt[tid] = 0;
  __syncthreads();
  int nvec = (eend - ebeg) & ~3;
  for (int i = ebeg + tid * 4; i < ebeg + nvec; i += 1024) {
    uint4 r = *(const uint4*)(recs + i);
    atomicAdd(&cnt[r.x & 255u], 1); atomicAdd(&cnt[r.y & 255u], 1);
    atomicAdd(&cnt[r.z & 255u], 1); atomicAdd(&cnt[r.w & 255u], 1);
  }
  for (int i = ebeg + nvec + tid; i < eend; i += 256) atomicAdd(&cnt[recs[i] & 255u], 1);
  __syncthreads();
  int v = cnt[tid];
  int lane = tid & 63, w = tid >> 6;
  int x_ = v;
#pragma unroll
  for (int d = 1; d < 64; d <<= 1) {
    int t = __shfl_up(x_, d);
    if (lane >= d) x_ += t;
  }
  if (lane == 63) wtot[w] = x_;
  __syncthreads();
  int pre = 0;
  for (int i = 0; i < w; ++i) pre += wtot[i];
  int gpos = ebeg + (x_ - v) + pre;
  int node = k * 256 + tid;
  if (node < N) {
    offs[node] = gpos;
    float is = rsqrtf(1.0f + (float)v);
    inv_sqrt[node] = is;
    const float* xr = x + (size_t)node * 5;
    float* xo = xp + (size_t)node * 5;
    xo[0] = xr[0] * is; xo[1] = xr[1] * is; xo[2] = xr[2] * is;
    xo[3] = xr[3] * is; xo[4] = xr[4] * is;
  }
  cur[tid] = gpos;
  if (k == NB - 1 && tid == 0) offs[N] = E;
  __syncthreads();
  for (int i = ebeg + tid * 4; i < ebeg + nvec; i += 1024) {
    uint4 r = *(const uint4*)(recs + i);
    int p0 = atomicAdd(&cur[r.x & 255u], 1); srcs[p0] = (int)(r.x >> 8);
    int p1 = atomicAdd(&cur[r.y & 255u], 1); srcs[p1] = (int)(r.y >> 8);
    int p2 = atomicAdd(&cur[r.z & 255u], 1); srcs[p2] = (int)(r.z >> 8);
    int p3 = atomicAdd(&cur[r.w & 255u], 1); srcs[p3] = (int)(r.w >> 8);
  }
  for (int i = ebeg + nvec + tid; i < eend; i += 256) {
    unsigned r = recs[i];
    int pos = atomicAdd(&cur[r & 255u], 1);
    srcs[pos] = (int)(r >> 8);
  }
}

// ---------------- layer kernels ----------------

// layers 1+2a fused, 2 nodes/wave; xp pre-scaled so edge loop is pure adds.
// Output prescaled, LINEAR layout: hp[node][64] = (relu((A x)W1+b1) @ W2) * inv_sqrt[node]
__global__ void k_l12(const float* __restrict__ xp, const int* __restrict__ offs,
                      const int* __restrict__ srcs, const float* __restrict__ inv_sqrt,
                      const float* __restrict__ W1, const float* __restrict__ b1,
                      const float* __restrict__ W2, float* __restrict__ hp, int n) {
  __shared__ float hrow[4][2][64];
  int tid = threadIdx.x;
  int lane = tid & 63, w = tid >> 6;
  int hl = lane & 31, half = lane >> 5;
  float w1r[5];
#pragma unroll
  for (int k = 0; k < 5; ++k) w1r[k] = W1[k * 64 + lane];
  float bias = b1[lane];
  float wreg[64];
#pragma unroll
  for (int k = 0; k < 64; ++k) wreg[k] = W2[k * 64 + lane];
  float* slotA = &hrow[w][0][0];
  float* slotB = &hrow[w][1][0];
  int wid0 = (blockIdx.x * blockDim.x + tid) >> 6;
  int nw = (gridDim.x * blockDim.x) >> 6;
  for (int i2 = wid0 * 2; i2 < n; i2 += nw * 2) {
    int iA = i2, iB = i2 + 1;
    int node = (half == 0) ? iA : iB;
    bool valid = node < n;
    float a0 = 0.f, a1 = 0.f, a2 = 0.f, a3 = 0.f, a4 = 0.f;
    float isd = 0.f;
    if (valid) {
      isd = inv_sqrt[node];
      int beg = offs[node], end = offs[node + 1];
      for (int j = beg + hl; j < end; j += 32) {
        int s = srcs[j];
        const float* xs = xp + (size_t)s * 5;
        float4 xv = *(const float4*)xs;   // 4B-aligned dwordx4 (HW-legal)
        float x4 = xs[4];
        a0 += xv.x; a1 += xv.y; a2 += xv.z; a3 += xv.w; a4 += x4;
      }
    }
#pragma unroll
    for (int d = 16; d; d >>= 1) {
      a0 += __shfl_xor(a0, d); a1 += __shfl_xor(a1, d); a2 += __shfl_xor(a2, d);
      a3 += __shfl_xor(a3, d); a4 += __shfl_xor(a4, d);
    }
    if (valid) {
      const float* xi = xp + (size_t)node * 5;
      a0 = (a0 + xi[0]) * isd; a1 = (a1 + xi[1]) * isd; a2 = (a2 + xi[2]) * isd;
      a3 = (a3 + xi[3]) * isd; a4 = (a4 + xi[4]) * isd;
    }
    float aA0 = __shfl(a0, hl),      aA1 = __shfl(a1, hl),      aA2 = __shfl(a2, hl);
    float aA3 = __shfl(a3, hl),      aA4 = __shfl(a4, hl);
    float aB0 = __shfl(a0, hl | 32), aB1 = __shfl(a1, hl | 32), aB2 = __shfl(a2, hl | 32);
    float aB3 = __shfl(a3, hl | 32), aB4 = __shfl(a4, hl | 32);
    float isdA = __shfl(isd, 0), isdB = __shfl(isd, 32);
    float hA = bias;
    hA = fmaf(aA0, w1r[0], hA); hA = fmaf(aA1, w1r[1], hA); hA = fmaf(aA2, w1r[2], hA);
    hA = fmaf(aA3, w1r[3], hA); hA = fmaf(aA4, w1r[4], hA);
    hA = fmaxf(hA, 0.f);
    float hB = bias;
    hB = fmaf(aB0, w1r[0], hB); hB = fmaf(aB1, w1r[1], hB); hB = fmaf(aB2, w1r[2], hB);
    hB = fmaf(aB3, w1r[3], hB); hB = fmaf(aB4, w1r[4], hB);
    hB = fmaxf(hB, 0.f);
    slotA[lane] = hA;
    slotB[lane] = hB;
    float ac0 = 0.f, ac1 = 0.f, ac2 = 0.f, ac3 = 0.f;
#pragma unroll
    for (int k4 = 0; k4 < 16; ++k4) {
      float4 hq = *(const float4*)&slotA[k4 * 4];
      ac0 = fmaf(hq.x, wreg[k4 * 4],     ac0);
      ac1 = fmaf(hq.y, wreg[k4 * 4 + 1], ac1);
      ac2 = fmaf(hq.z, wreg[k4 * 4 + 2], ac2);
      ac3 = fmaf(hq.w, wreg[k4 * 4 + 3], ac3);
    }
    hp[(size_t)iA * 64 + lane] = ((ac0 + ac1) + (ac2 + ac3)) * isdA;
    if (iB < n) {
      float bc0 = 0.f, bc1 = 0.f, bc2 = 0.f, bc3 = 0.f;
#pragma unroll
      for (int k4 = 0; k4 < 16; ++k4) {
        float4 hq = *(const float4*)&slotB[k4 * 4];
        bc0 = fmaf(hq.x, wreg[k4 * 4],     bc0);
        bc1 = fmaf(hq.y, wreg[k4 * 4 + 1], bc1);
        bc2 = fmaf(hq.z, wreg[k4 * 4 + 2], bc2);
        bc3 = fmaf(hq.w, wreg[k4 * 4 + 3], bc3);
      }
      hp[(size_t)iB * 64 + lane] = ((bc0 + bc1) + (bc2 + bc3)) * isdB;
    }
  }
}

// layers 2b+3a fused: h2 = relu(isd*(sum hp[src] + hp[self]) + b2); h3p = (h2 @ W3)*isd
// Sub-slot owns a CONTIGUOUS run of 4 edges -> one int4 index load + 4 float4 rows
// in flight per 16-lane group (16 rows/wave/iter).
__global__ void k_agg64w3(const float* __restrict__ hp, const int* __restrict__ offs,
                          const int* __restrict__ srcs, const float* __restrict__ inv_sqrt,
                          const float* __restrict__ b2, const float* __restrict__ W3,
                          float* __restrict__ h3p, int n) {
  int wid = (blockIdx.x * blockDim.x + threadIdx.x) >> 6;
  int lane = threadIdx.x & 63;
  if (wid >= n) return;
  int sub = lane >> 4;
  int fl  = lane & 15;
  float w30[4], w31[4];
#pragma unroll
  for (int q = 0; q < 4; ++q) {
    w30[q] = W3[(fl * 4 + q) * 2];
    w31[q] = W3[(fl * 4 + q) * 2 + 1];
  }
  int beg = offs[wid], end = offs[wid + 1];
  float isd = inv_sqrt[wid];
  float ax0 = 0.f, ay0 = 0.f, az0 = 0.f, aw0 = 0.f;
  float ax1 = 0.f, ay1 = 0.f, az1 = 0.f, aw1 = 0.f;
  int c = beg;
  for (; c + 16 <= end; c += 16) {
    int j = c + (sub << 2);
    int4 sv = *(const int4*)(srcs + j);   // 4B-aligned dwordx4 (HW-legal)
    float4 r0 = *(const float4*)(hp + (size_t)sv.x * 64 + fl * 4);
    float4 r1 = *(const float4*)(hp + (size_t)sv.y * 64 + fl * 4);
    float4 r2 = *(const float4*)(hp + (size_t)sv.z * 64 + fl * 4);
    float4 r3 = *(const float4*)(hp + (size_t)sv.w * 64 + fl * 4);
    ax0 += r0.x; ay0 += r0.y; az0 += r0.z; aw0 += r0.w;
    ax1 += r1.x; ay1 += r1.y; az1 += r1.z; aw1 += r1.w;
    ax0 += r2.x; ay0 += r2.y; az0 += r2.z; aw0 += r2.w;
    ax1 += r3.x; ay1 += r3.y; az1 += r3.z; aw1 += r3.w;
  }
  for (int j = c + sub; j < end; j += 4) {
    int s0 = srcs[j];
    float4 r0 = *(const float4*)(hp + (size_t)s0 * 64 + fl * 4);
    ax0 += r0.x; ay0 += r0.y; az0 += r0.z; aw0 += r0.w;
  }
  float ax = ax0 + ax1, ay = ay0 + ay1, az = az0 + az1, aw = aw0 + aw1;
  ax += __shfl_xor(ax, 16); ay += __shfl_xor(ay, 16);
  az += __shfl_xor(az, 16); aw += __shfl_xor(aw, 16);
  ax += __shfl_xor(ax, 32); ay += __shfl_xor(ay, 32);
  az += __shfl_xor(az, 32); aw += __shfl_xor(aw, 32);
  float4 self = *(const float4*)(hp + (size_t)wid * 64 + fl * 4);
  float4 bb   = *(const float4*)(b2 + fl * 4);
  float hx = fmaxf(fmaf(isd, ax + self.x, bb.x), 0.f);
  float hy = fmaxf(fmaf(isd, ay + self.y, bb.y), 0.f);
  float hz = fmaxf(fmaf(isd, az + self.z, bb.z), 0.f);
  float hw = fmaxf(fmaf(isd, aw + self.w, bb.w), 0.f);
  float p0 = hx * w30[0] + hy * w30[1] + hz * w30[2] + hw * w30[3];
  float p1 = hx * w31[0] + hy * w31[1] + hz * w31[2] + hw * w31[3];
#pragma unroll
  for (int d = 8; d; d >>= 1) { p0 += __shfl_xor(p0, d); p1 += __shfl_xor(p1, d); }
  if (lane == 0) {
    h3p[(size_t)wid * 2]     = p0 * isd;
    h3p[(size_t)wid * 2 + 1] = p1 * isd;
  }
}

// out = isd*(sum h3p[src] + h3p[self]) + b3  — TWO nodes per wave (32-lane halves)
__global__ void k_agg2(const float* __restrict__ h3p, const int* __restrict__ offs,
                       const int* __restrict__ srcs, const float* __restrict__ inv_sqrt,
                       const float* __restrict__ b3, float* __restrict__ out, int n) {
  int wv = (blockIdx.x * blockDim.x + threadIdx.x) >> 6;
  int lane = threadIdx.x & 63;
  int half = lane >> 5, hl = lane & 31;
  int node = wv * 2 + half;
  float a0 = 0.f, a1 = 0.f;
  if (node < n) {
    int beg = offs[node], end = offs[node + 1];
    for (int j = beg + hl; j < end; j += 32) {
      int s = srcs[j];
      float2 hv = *(const float2*)(h3p + (size_t)s * 2);
      a0 += hv.x; a1 += hv.y;
    }
  }
#pragma unroll
  for (int d = 16; d; d >>= 1) { a0 += __shfl_xor(a0, d); a1 += __shfl_xor(a1, d); }
  if (node < n && hl == 0) {
    float isd = inv_sqrt[node];
    float2 self = *(const float2*)(h3p + (size_t)node * 2);
    out[(size_t)node * 2]     = fmaf(isd, a0 + self.x, b3[0]);
    out[(size_t)node * 2 + 1] = fmaf(isd, a1 + self.y, b3[1]);
  }
}

// ---------------- launcher ----------------

extern "C" void kernel_launch(void* const* d_in, const int* in_sizes, int n_in,
                              void* d_out, int out_size, void* d_ws, size_t ws_size,
                              hipStream_t stream) {
  const float* x  = (const float*)d_in[0];
  const int*   ei = (const int*)d_in[1];
  const float* W1 = (const float*)d_in[2];
  const float* b1 = (const float*)d_in[3];
  const float* W2 = (const float*)d_in[4];
  const float* b2 = (const float*)d_in[5];
  const float* W3 = (const float*)d_in[6];
  const float* b3 = (const float*)d_in[7];
  float* out = (float*)d_out;

  const int N = in_sizes[0] / 5;
  const int E = in_sizes[1] / 2;
  const int* src = ei;
  const int* dst = ei + E;

  const int NB = (N + 255) >> 8;
  const int chunk = (E + CB - 1) / CB;
  const int n2 = NB * CB;
  const int nb2 = (n2 + 1023) / 1024;   // <= 256

  char* p = (char*)d_ws;
  auto alloc = [&](size_t bytes) {
    char* r = p;
    p += (bytes + 255) & ~(size_t)255;
    return r;
  };
  int*      histG     = (int*)alloc((size_t)n2 * 4);
  int*      histS     = (int*)alloc((size_t)n2 * 4);
  int*      blockSums = (int*)alloc((size_t)nb2 * 4);
  int*      blockOffs = (int*)alloc((size_t)(nb2 + 1) * 4);
  unsigned* recs      = (unsigned*)alloc((size_t)E * 4);
  int*      srcs      = (int*)alloc((size_t)E * 4);
  int*      offs      = (int*)alloc((size_t)(N + 1) * 4);
  float*    inv_sqrt  = (float*)alloc((size_t)N * 4);
  float*    xp        = (float*)alloc((size_t)N * 5 * 4);
  float*    hp        = (float*)alloc((size_t)N * 64 * 4);
  float*    h3p       = (float*)alloc((size_t)N * 2 * 4);

  const int wavesBlocks = (N * 64 + 255) / 256;       // one wave per node
  const int pairs = (N + 1) / 2;
  const int pairBlocks = (pairs * 64 + 255) / 256;    // one wave per 2 nodes

  // CSR build via stable bucket sort — zero global atomics
  k_hist<<<CB, 256, 0, stream>>>(dst, histG, E, NB, chunk);
  k_scan_local<<<nb2, 1024, 0, stream>>>(histG, histS, blockSums, n2);
  k_scan_blocks<<<1, 256, 0, stream>>>(blockSums, blockOffs, nb2);
  k_scatter<<<CB, 256, 0, stream>>>(src, dst, histS, blockOffs, recs, E, NB, chunk);
  k_build<<<NB, 256, 0, stream>>>(recs, histS, blockOffs, x, offs, inv_sqrt, xp, srcs, N, NB, E);

  // layers 1+2a fused: hp[node][64] = (relu((A x) W1 + b1) @ W2) * inv_sqrt
  k_l12<<<2048, 256, 0, stream>>>(xp, offs, srcs, inv_sqrt, W1, b1, W2, hp, N);
  // layers 2b+3a fused: h3p = (relu(isd*(sum hp) + b2) @ W3) * isd
  k_agg64w3<<<wavesBlocks, 256, 0, stream>>>(hp, offs, srcs, inv_sqrt, b2, W3, h3p, N);
  // layer 3 aggregation (2 nodes/wave)
  k_agg2<<<pairBlocks, 256, 0, stream>>>(h3p, offs, srcs, inv_sqrt, b3, out, N);
}

// Round 11
// 225.382 us; speedup vs baseline: 1.6963x; 1.0030x over previous
//
#include <hip/hip_runtime.h>

#define CB 256        // chunk-blocks for hist/scatter
#define MAXNB 1024    // max buckets (N <= 262144)

// ---------------- bucket-sort CSR build (no global atomics) ----------------

__global__ void k_hist(const int* __restrict__ dst, int* __restrict__ histG,
                       int E, int NB, int chunk) {
  __shared__ int hist[MAXNB];
  int b = blockIdx.x, tid = threadIdx.x;
  for (int k = tid; k < NB; k += 256) hist[k] = 0;
  __syncthreads();
  int beg = b * chunk, end = min(E, beg + chunk);
  int nvec = (end - beg) & ~3;
  for (int i = beg + tid * 4; i < beg + nvec; i += 1024) {
    int4 d = *(const int4*)(dst + i);
    atomicAdd(&hist[d.x >> 8], 1); atomicAdd(&hist[d.y >> 8], 1);
    atomicAdd(&hist[d.z >> 8], 1); atomicAdd(&hist[d.w >> 8], 1);
  }
  for (int i = beg + nvec + tid; i < end; i += 256) atomicAdd(&hist[dst[i] >> 8], 1);
  __syncthreads();
  for (int k = tid; k < NB; k += 256) histG[(size_t)k * CB + b] = hist[k];
}

__global__ void k_scan_local(const int* __restrict__ in, int* __restrict__ out,
                             int* __restrict__ blockSums, int n) {
  __shared__ int wsum[16];
  __shared__ int wpre[16];
  int tid = threadIdx.x;
  int gid = blockIdx.x * 1024 + tid;
  int v = (gid < n) ? in[gid] : 0;
  int lane = tid & 63, wv = tid >> 6;
  int x = v;
#pragma unroll
  for (int d = 1; d < 64; d <<= 1) {
    int t = __shfl_up(x, d);
    if (lane >= d) x += t;
  }
  if (lane == 63) wsum[wv] = x;
  __syncthreads();
  if (tid == 0) {
    int run = 0;
#pragma unroll
    for (int i = 0; i < 16; ++i) { wpre[i] = run; run += wsum[i]; }
    blockSums[blockIdx.x] = run;
  }
  __syncthreads();
  if (gid < n) out[gid] = x - v + wpre[wv];
}

// parallel scan of block sums (single block, 256 threads, nb <= 256)
__global__ void k_scan_blocks(const int* __restrict__ blockSums, int* __restrict__ blockOffs, int nb) {
  __shared__ int wtot[4];
  int tid = threadIdx.x;
  int lane = tid & 63, w = tid >> 6;
  int v = (tid < nb) ? blockSums[tid] : 0;
  int x = v;
#pragma unroll
  for (int d = 1; d < 64; d <<= 1) {
    int t = __shfl_up(x, d);
    if (lane >= d) x += t;
  }
  if (lane == 63) wtot[w] = x;
  __syncthreads();
  int pre = 0;
  for (int i = 0; i < w; ++i) pre += wtot[i];
  int ex = x - v + pre;
  if (tid < nb) blockOffs[tid] = ex;
  if (tid == nb - 1) blockOffs[nb] = ex + v;
}

__global__ void k_scatter(const int* __restrict__ src, const int* __restrict__ dst,
                          const int* __restrict__ histS, const int* __restrict__ blockOffs,
                          unsigned* __restrict__ recs, int E, int NB, int chunk) {
  __shared__ int cur[MAXNB];
  int b = blockIdx.x, tid = threadIdx.x;
  for (int k = tid; k < NB; k += 256) {
    int gid = k * CB + b;
    cur[k] = histS[gid] + blockOffs[gid >> 10];
  }
  __syncthreads();
  int beg = b * chunk, end = min(E, beg + chunk);
  int nvec = (end - beg) & ~3;
  for (int i = beg + tid * 4; i < beg + nvec; i += 1024) {
    int4 s4 = *(const int4*)(src + i);
    int4 d4 = *(const int4*)(dst + i);
    int p0 = atomicAdd(&cur[d4.x >> 8], 1);
    recs[p0] = ((unsigned)s4.x << 8) | (unsigned)(d4.x & 255);
    int p1 = atomicAdd(&cur[d4.y >> 8], 1);
    recs[p1] = ((unsigned)s4.y << 8) | (unsigned)(d4.y & 255);
    int p2 = atomicAdd(&cur[d4.z >> 8], 1);
    recs[p2] = ((unsigned)s4.z << 8) | (unsigned)(d4.z & 255);
    int p3 = atomicAdd(&cur[d4.w >> 8], 1);
    recs[p3] = ((unsigned)s4.w << 8) | (unsigned)(d4.w & 255);
  }
  for (int i = beg + nvec + tid; i < end; i += 256) {
    int s = src[i], d = dst[i];
    int pos = atomicAdd(&cur[d >> 8], 1);
    recs[pos] = ((unsigned)s << 8) | (unsigned)(d & 255);
  }
}

// per-bucket CSR finalize; also writes inv_sqrt and prescaled xp = x * inv_sqrt
__global__ void k_build(const unsigned* __restrict__ recs, const int* __restrict__ histS,
                        const int* __restrict__ blockOffs, const float* __restrict__ x,
                        int* __restrict__ offs, float* __restrict__ inv_sqrt,
                        float* __restrict__ xp, int* __restrict__ srcs,
                        int N, int NB, int E) {
  __shared__ int cnt[256];
  __shared__ int cur[256];
  __shared__ int wtot[4];
  int k = blockIdx.x, tid = threadIdx.x;
  int g0 = k * CB;
  int ebeg = histS[g0] + blockOffs[g0 >> 10];
  int eend = E;
  if (k + 1 < NB) {
    int g1 = (k + 1) * CB;
    eend = histS[g1] + blockOffs[g1 >> 10];
  }
  cnt[tid] = 0;
  __syncthreads();
  int nvec = (eend - ebeg) & ~3;
  for (int i = ebeg + tid * 4; i < ebeg + nvec; i += 1024) {
    uint4 r = *(const uint4*)(recs + i);
    atomicAdd(&cnt[r.x & 255u], 1); atomicAdd(&cnt[r.y & 255u], 1);
    atomicAdd(&cnt[r.z & 255u], 1); atomicAdd(&cnt[r.w & 255u], 1);
  }
  for (int i = ebeg + nvec + tid; i < eend; i += 256) atomicAdd(&cnt[recs[i] & 255u], 1);
  __syncthreads();
  int v = cnt[tid];
  int lane = tid & 63, w = tid >> 6;
  int x_ = v;
#pragma unroll
  for (int d = 1; d < 64; d <<= 1) {
    int t = __shfl_up(x_, d);
    if (lane >= d) x_ += t;
  }
  if (lane == 63) wtot[w] = x_;
  __syncthreads();
  int pre = 0;
  for (int i = 0; i < w; ++i) pre += wtot[i];
  int gpos = ebeg + (x_ - v) + pre;
  int node = k * 256 + tid;
  if (node < N) {
    offs[node] = gpos;
    float is = rsqrtf(1.0f + (float)v);
    inv_sqrt[node] = is;
    const float* xr = x + (size_t)node * 5;
    float* xo = xp + (size_t)node * 5;
    xo[0] = xr[0] * is; xo[1] = xr[1] * is; xo[2] = xr[2] * is;
    xo[3] = xr[3] * is; xo[4] = xr[4] * is;
  }
  cur[tid] = gpos;
  if (k == NB - 1 && tid == 0) offs[N] = E;
  __syncthreads();
  for (int i = ebeg + tid * 4; i < ebeg + nvec; i += 1024) {
    uint4 r = *(const uint4*)(recs + i);
    int p0 = atomicAdd(&cur[r.x & 255u], 1); srcs[p0] = (int)(r.x >> 8);
    int p1 = atomicAdd(&cur[r.y & 255u], 1); srcs[p1] = (int)(r.y >> 8);
    int p2 = atomicAdd(&cur[r.z & 255u], 1); srcs[p2] = (int)(r.z >> 8);
    int p3 = atomicAdd(&cur[r.w & 255u], 1); srcs[p3] = (int)(r.w >> 8);
  }
  for (int i = ebeg + nvec + tid; i < eend; i += 256) {
    unsigned r = recs[i];
    int pos = atomicAdd(&cur[r & 255u], 1);
    srcs[pos] = (int)(r >> 8);
  }
}

// ---------------- layer kernels ----------------

// layer 1 only, 2 nodes/wave: h1p[node][64] = relu((A_norm x) W1 + b1) * inv_sqrt[node]
// (W2 GEMV moved downstream via A(h1 W2) = (A h1) W2). No LDS, no wreg.
__global__ void k_l1(const float* __restrict__ xp, const int* __restrict__ offs,
                     const int* __restrict__ srcs, const float* __restrict__ inv_sqrt,
                     const float* __restrict__ W1, const float* __restrict__ b1,
                     float* __restrict__ h1p, int n) {
  int tid = threadIdx.x;
  int lane = tid & 63;
  int hl = lane & 31, half = lane >> 5;
  float w1r[5];
#pragma unroll
  for (int k = 0; k < 5; ++k) w1r[k] = W1[k * 64 + lane];
  float bias = b1[lane];
  int wid0 = (blockIdx.x * blockDim.x + tid) >> 6;
  int nw = (gridDim.x * blockDim.x) >> 6;
  for (int i2 = wid0 * 2; i2 < n; i2 += nw * 2) {
    int iA = i2, iB = i2 + 1;
    int node = (half == 0) ? iA : iB;
    bool valid = node < n;
    float a0 = 0.f, a1 = 0.f, a2 = 0.f, a3 = 0.f, a4 = 0.f;
    float isd = 0.f;
    if (valid) {
      isd = inv_sqrt[node];
      int beg = offs[node], end = offs[node + 1];
      for (int j = beg + hl; j < end; j += 32) {
        int s = srcs[j];
        const float* xs = xp + (size_t)s * 5;
        float4 xv = *(const float4*)xs;   // 4B-aligned dwordx4 (HW-legal)
        float x4 = xs[4];
        a0 += xv.x; a1 += xv.y; a2 += xv.z; a3 += xv.w; a4 += x4;
      }
    }
#pragma unroll
    for (int d = 16; d; d >>= 1) {
      a0 += __shfl_xor(a0, d); a1 += __shfl_xor(a1, d); a2 += __shfl_xor(a2, d);
      a3 += __shfl_xor(a3, d); a4 += __shfl_xor(a4, d);
    }
    if (valid) {
      const float* xi = xp + (size_t)node * 5;
      a0 = (a0 + xi[0]) * isd; a1 = (a1 + xi[1]) * isd; a2 = (a2 + xi[2]) * isd;
      a3 = (a3 + xi[3]) * isd; a4 = (a4 + xi[4]) * isd;
    }
    // broadcast each node's xagg to all lanes
    float aA0 = __shfl(a0, hl),      aA1 = __shfl(a1, hl),      aA2 = __shfl(a2, hl);
    float aA3 = __shfl(a3, hl),      aA4 = __shfl(a4, hl);
    float aB0 = __shfl(a0, hl | 32), aB1 = __shfl(a1, hl | 32), aB2 = __shfl(a2, hl | 32);
    float aB3 = __shfl(a3, hl | 32), aB4 = __shfl(a4, hl | 32);
    float isdA = __shfl(isd, 0), isdB = __shfl(isd, 32);
    float hA = bias;
    hA = fmaf(aA0, w1r[0], hA); hA = fmaf(aA1, w1r[1], hA); hA = fmaf(aA2, w1r[2], hA);
    hA = fmaf(aA3, w1r[3], hA); hA = fmaf(aA4, w1r[4], hA);
    h1p[(size_t)iA * 64 + lane] = fmaxf(hA, 0.f) * isdA;
    if (iB < n) {
      float hB = bias;
      hB = fmaf(aB0, w1r[0], hB); hB = fmaf(aB1, w1r[1], hB); hB = fmaf(aB2, w1r[2], hB);
      hB = fmaf(aB3, w1r[3], hB); hB = fmaf(aB4, w1r[4], hB);
      h1p[(size_t)iB * 64 + lane] = fmaxf(hB, 0.f) * isdB;
    }
  }
}

// layers 2+3a fused: agg = sum h1p[src] + h1p[self]  (pure float4 adds, 16 rows in flight)
// then h2 = relu(isd * (agg @ W2) + b2); h3p = (h2 @ W3) * isd.
// GEMV runs in the gather kernel's latency shadow (DS/VALU idle during vmem waits).
__global__ void k_agg64w3(const float* __restrict__ h1p, const int* __restrict__ offs,
                          const int* __restrict__ srcs, const float* __restrict__ inv_sqrt,
                          const float* __restrict__ W2, const float* __restrict__ b2,
                          const float* __restrict__ W3, float* __restrict__ h3p, int n) {
  __shared__ float aggrow[4][68];   // one 64-float row per wave (+pad)
  int tid = threadIdx.x;
  int lane = tid & 63, w = tid >> 6;
  float wreg[64];
#pragma unroll
  for (int k = 0; k < 64; ++k) wreg[k] = W2[k * 64 + lane];
  float w30 = W3[lane * 2], w31 = W3[lane * 2 + 1];
  float b2v = b2[lane];
  float* slot = &aggrow[w][0];
  int sub = lane >> 4;
  int fl  = lane & 15;
  int wid0 = (blockIdx.x * blockDim.x + tid) >> 6;
  int nw = (gridDim.x * blockDim.x) >> 6;
  for (int i = wid0; i < n; i += nw) {
    int beg = offs[i], end = offs[i + 1];
    float isd = inv_sqrt[i];
    float ax0 = 0.f, ay0 = 0.f, az0 = 0.f, aw0 = 0.f;
    float ax1 = 0.f, ay1 = 0.f, az1 = 0.f, aw1 = 0.f;
    int c = beg;
    for (; c + 16 <= end; c += 16) {
      int j = c + (sub << 2);
      int4 sv = *(const int4*)(srcs + j);   // contiguous run of 4 per sub
      float4 r0 = *(const float4*)(h1p + (size_t)sv.x * 64 + fl * 4);
      float4 r1 = *(const float4*)(h1p + (size_t)sv.y * 64 + fl * 4);
      float4 r2 = *(const float4*)(h1p + (size_t)sv.z * 64 + fl * 4);
      float4 r3 = *(const float4*)(h1p + (size_t)sv.w * 64 + fl * 4);
      ax0 += r0.x; ay0 += r0.y; az0 += r0.z; aw0 += r0.w;
      ax1 += r1.x; ay1 += r1.y; az1 += r1.z; aw1 += r1.w;
      ax0 += r2.x; ay0 += r2.y; az0 += r2.z; aw0 += r2.w;
      ax1 += r3.x; ay1 += r3.y; az1 += r3.z; aw1 += r3.w;
    }
    for (int j = c + sub; j < end; j += 4) {
      int s0 = srcs[j];
      float4 r0 = *(const float4*)(h1p + (size_t)s0 * 64 + fl * 4);
      ax0 += r0.x; ay0 += r0.y; az0 += r0.z; aw0 += r0.w;
    }
    float ax = ax0 + ax1, ay = ay0 + ay1, az = az0 + az1, aw = aw0 + aw1;
    ax += __shfl_xor(ax, 16); ay += __shfl_xor(ay, 16);
    az += __shfl_xor(az, 16); aw += __shfl_xor(aw, 16);
    ax += __shfl_xor(ax, 32); ay += __shfl_xor(ay, 32);
    az += __shfl_xor(az, 32); aw += __shfl_xor(aw, 32);
    // + self row
    float4 self = *(const float4*)(h1p + (size_t)i * 64 + fl * 4);
    ax += self.x; ay += self.y; az += self.z; aw += self.w;
    // stage agg row in wave-private LDS slot (sub 0 lanes hold full row)
    if (sub == 0) {
      float4 q; q.x = ax; q.y = ay; q.z = az; q.w = aw;
      *(float4*)&slot[fl * 4] = q;
    }
    // W2 GEMV: broadcast b128 reads (DS pipe in-order per wave)
    float z0 = 0.f, z1 = 0.f, z2 = 0.f, z3 = 0.f;
#pragma unroll
    for (int k4 = 0; k4 < 16; ++k4) {
      float4 q = *(const float4*)&slot[k4 * 4];
      z0 = fmaf(q.x, wreg[k4 * 4],     z0);
      z1 = fmaf(q.y, wreg[k4 * 4 + 1], z1);
      z2 = fmaf(q.z, wreg[k4 * 4 + 2], z2);
      z3 = fmaf(q.w, wreg[k4 * 4 + 3], z3);
    }
    float z = (z0 + z1) + (z2 + z3);
    float h2 = fmaxf(fmaf(isd, z, b2v), 0.f);   // lane = feature
    float p0 = h2 * w30, p1 = h2 * w31;
#pragma unroll
    for (int d = 32; d; d >>= 1) { p0 += __shfl_xor(p0, d); p1 += __shfl_xor(p1, d); }
    if (lane == 0) {
      h3p[(size_t)i * 2]     = p0 * isd;
      h3p[(size_t)i * 2 + 1] = p1 * isd;
    }
  }
}

// out = isd*(sum h3p[src] + h3p[self]) + b3  — TWO nodes per wave (32-lane halves)
__global__ void k_agg2(const float* __restrict__ h3p, const int* __restrict__ offs,
                       const int* __restrict__ srcs, const float* __restrict__ inv_sqrt,
                       const float* __restrict__ b3, float* __restrict__ out, int n) {
  int wv = (blockIdx.x * blockDim.x + threadIdx.x) >> 6;
  int lane = threadIdx.x & 63;
  int half = lane >> 5, hl = lane & 31;
  int node = wv * 2 + half;
  float a0 = 0.f, a1 = 0.f;
  if (node < n) {
    int beg = offs[node], end = offs[node + 1];
    for (int j = beg + hl; j < end; j += 32) {
      int s = srcs[j];
      float2 hv = *(const float2*)(h3p + (size_t)s * 2);
      a0 += hv.x; a1 += hv.y;
    }
  }
#pragma unroll
  for (int d = 16; d; d >>= 1) { a0 += __shfl_xor(a0, d); a1 += __shfl_xor(a1, d); }
  if (node < n && hl == 0) {
    float isd = inv_sqrt[node];
    float2 self = *(const float2*)(h3p + (size_t)node * 2);
    out[(size_t)node * 2]     = fmaf(isd, a0 + self.x, b3[0]);
    out[(size_t)node * 2 + 1] = fmaf(isd, a1 + self.y, b3[1]);
  }
}

// ---------------- launcher ----------------

extern "C" void kernel_launch(void* const* d_in, const int* in_sizes, int n_in,
                              void* d_out, int out_size, void* d_ws, size_t ws_size,
                              hipStream_t stream) {
  const float* x  = (const float*)d_in[0];
  const int*   ei = (const int*)d_in[1];
  const float* W1 = (const float*)d_in[2];
  const float* b1 = (const float*)d_in[3];
  const float* W2 = (const float*)d_in[4];
  const float* b2 = (const float*)d_in[5];
  const float* W3 = (const float*)d_in[6];
  const float* b3 = (const float*)d_in[7];
  float* out = (float*)d_out;

  const int N = in_sizes[0] / 5;
  const int E = in_sizes[1] / 2;
  const int* src = ei;
  const int* dst = ei + E;

  const int NB = (N + 255) >> 8;
  const int chunk = (E + CB - 1) / CB;
  const int n2 = NB * CB;
  const int nb2 = (n2 + 1023) / 1024;   // <= 256

  char* p = (char*)d_ws;
  auto alloc = [&](size_t bytes) {
    char* r = p;
    p += (bytes + 255) & ~(size_t)255;
    return r;
  };
  int*      histG     = (int*)alloc((size_t)n2 * 4);
  int*      histS     = (int*)alloc((size_t)n2 * 4);
  int*      blockSums = (int*)alloc((size_t)nb2 * 4);
  int*      blockOffs = (int*)alloc((size_t)(nb2 + 1) * 4);
  unsigned* recs      = (unsigned*)alloc((size_t)E * 4);
  int*      srcs      = (int*)alloc((size_t)E * 4);
  int*      offs      = (int*)alloc((size_t)(N + 1) * 4);
  float*    inv_sqrt  = (float*)alloc((size_t)N * 4);
  float*    xp        = (float*)alloc((size_t)N * 5 * 4);
  float*    hp        = (float*)alloc((size_t)N * 64 * 4);
  float*    h3p       = (float*)alloc((size_t)N * 2 * 4);

  const int pairs = (N + 1) / 2;
  const int pairBlocks = (pairs * 64 + 255) / 256;    // one wave per 2 nodes

  // CSR build via stable bucket sort — zero global atomics
  k_hist<<<CB, 256, 0, stream>>>(dst, histG, E, NB, chunk);
  k_scan_local<<<nb2, 1024, 0, stream>>>(histG, histS, blockSums, n2);
  k_scan_blocks<<<1, 256, 0, stream>>>(blockSums, blockOffs, nb2);
  k_scatter<<<CB, 256, 0, stream>>>(src, dst, histS, blockOffs, recs, E, NB, chunk);
  k_build<<<NB, 256, 0, stream>>>(recs, histS, blockOffs, x, offs, inv_sqrt, xp, srcs, N, NB, E);

  // layer 1: h1p[node][64] = relu((A x) W1 + b1) * inv_sqrt   (no GEMV here)
  k_l1<<<2048, 256, 0, stream>>>(xp, offs, srcs, inv_sqrt, W1, b1, hp, N);
  // layers 2+3a fused: gather h1p, then (agg @ W2) under the gather's latency shadow
  k_agg64w3<<<2048, 256, 0, stream>>>(hp, offs, srcs, inv_sqrt, W2, b2, W3, h3p, N);
  // layer 3 aggregation (2 nodes/wave)
  k_agg2<<<pairBlocks, 256, 0, stream>>>(h3p, offs, srcs, inv_sqrt, b3, out, N);
}